// Round 15
// baseline (526.954 us; speedup 1.0000x reference)
//
#include <hip/hip_runtime.h>
#include <hip/hip_bf16.h>

// SwinBlock r15: small-block GEMMs for the MLP (r9 geometries: more blocks/CU
// hides the per-block barrier stall better than wider tiles): mlp1 = 128x128
// 256-thr ~5 blocks/CU, mlp2 = 64x256 256-thr 3 blocks/CU, both full-M.
// qkv gemmW (fused gather) + projln1 + attn unchanged from r14. convW merged.
// B=32 H=W=56 C=256 NH=8 HD=32 WS=7 SS=3 L=49 nWin=64 -> 2048 windows, M=100352.

typedef unsigned short ushort_t;
typedef short bf16x8 __attribute__((ext_vector_type(8)));
typedef float f32x4 __attribute__((ext_vector_type(4)));

#define WAITV0 asm volatile("s_waitcnt vmcnt(0)" ::: "memory")
#define WAITV3 asm volatile("s_waitcnt vmcnt(3)" ::: "memory")
#define WAITV4 asm volatile("s_waitcnt vmcnt(4)" ::: "memory")
#define WAITL0 asm volatile("s_waitcnt lgkmcnt(0)" ::: "memory")
#define BAR    __builtin_amdgcn_s_barrier()
#define PRIO1  __builtin_amdgcn_s_setprio(1)
#define PRIO0  __builtin_amdgcn_s_setprio(0)

__device__ __forceinline__ float bf2f(unsigned short u) {
    union { unsigned int i; float f; } x; x.i = ((unsigned int)u) << 16; return x.f;
}
__device__ __forceinline__ unsigned short f2bf(float f) {
    union { float f; unsigned int i; } x; x.f = f;
    unsigned int r = x.i + 0x7fffu + ((x.i >> 16) & 1u);   // RNE
    return (unsigned short)(r >> 16);
}
__device__ __forceinline__ bf16x8 pack8(float4 a, float4 b) {
    bf16x8 r;
    r[0] = (short)f2bf(a.x); r[1] = (short)f2bf(a.y);
    r[2] = (short)f2bf(a.z); r[3] = (short)f2bf(a.w);
    r[4] = (short)f2bf(b.x); r[5] = (short)f2bf(b.y);
    r[6] = (short)f2bf(b.z); r[7] = (short)f2bf(b.w);
    return r;
}
__device__ __forceinline__ void gl_lds16(const ushort_t* g, ushort_t* l) {
    __builtin_amdgcn_global_load_lds((const __attribute__((address_space(1))) void*)g,
                                     (__attribute__((address_space(3))) void*)l, 16, 0, 0);
}
// exact-erf GELU via Abramowitz-Stegun 7.1.26 (max |err| 1.5e-7)
__device__ __forceinline__ float gelu_f(float v) {
    float s = v * 0.70710678118654752f;
    float ax = fabsf(s);
    float t = __builtin_amdgcn_rcpf(1.0f + 0.3275911f * ax);
    float poly = ((((1.061405429f * t - 1.453152027f) * t + 1.421413741f) * t
                   - 0.284496736f) * t + 0.254829592f) * t;
    float y = 1.0f - poly * __expf(-ax * ax);
    float e = (s < 0.f) ? -y : y;
    return 0.5f * v * (1.0f + e);
}

// row m of the windowed/shifted activation -> element offset into x[B,H,W,C]
__device__ __forceinline__ long swin_src_off(int m) {
    int n = m / 49, l = m - n * 49;
    int b = n >> 6, win = n & 63;
    int wh = win >> 3, ww = win & 7;
    int i = l / 7, j = l - i * 7;
    int hs = wh * 7 + i + 3; if (hs >= 56) hs -= 56;   // roll(-3)
    int ws = ww * 7 + j + 3; if (ws >= 56) ws -= 56;
    return ((long)(b * 56 + hs) * 56 + ws) * 256;
}

// ------- prep: all four weights fp32 -> bf16 [N][K] in ONE dispatch -------
// blocks [0,768): qkv_w copy; [768,1024): proj_w copy;
// [1024,2048): w1 transpose [256][1024]->[1024][256];
// [2048,3072): w2 transpose [1024][256]->[256][1024].
__global__ __launch_bounds__(256)
void convAll(const float* __restrict__ qkv_w, const float* __restrict__ proj_w,
             const float* __restrict__ w1, const float* __restrict__ w2,
             ushort_t* __restrict__ dq, ushort_t* __restrict__ dp,
             ushort_t* __restrict__ d1, ushort_t* __restrict__ d2)
{
    int b = blockIdx.x, tix = threadIdx.x;
    if (b < 768) {
        int idx = b * 256 + tix;
        dq[idx] = f2bf(qkv_w[idx]);
    } else if (b < 1024) {
        int idx = (b - 768) * 256 + tix;
        dp[idx] = f2bf(proj_w[idx]);
    } else if (b < 2048) {
        int idx = (b - 1024) * 256 + tix;
        int kk = idx & 255, nn = idx >> 8;           // d1[nn][kk] = w1[kk][nn]
        d1[idx] = f2bf(w1[(long)kk * 1024 + nn]);
    } else {
        int idx = (b - 2048) * 256 + tix;
        int kk = idx & 1023, nn = idx >> 10;         // d2[nn][kk] = w2[kk][nn]
        d2[idx] = f2bf(w2[(long)kk * 256 + nn]);
    }
}

// ---- gemmW: 128x256 tile, 512 thr, BK=32, 3-deep counted-vmcnt loop (qkv) ----
template<int ACT, int AMODE, int NCOLS>
__global__ __launch_bounds__(512)
void gemmW(const void* __restrict__ Av, const ushort_t* __restrict__ W,
           const float* __restrict__ bias, ushort_t* __restrict__ C,
           int M, int N, int K)
{
    constexpr int NA = (AMODE == 1) ? 2 : 3;
    __shared__ ushort_t As[NA * 4096];
    __shared__ ushort_t Bs[3 * 8192];
    const int t = threadIdx.x, lane = t & 63, w = t >> 6;
    const int cpx = gridDim.x >> 3;
    const int wg = (blockIdx.x & 7) * cpx + (blockIdx.x >> 3);
    const int row0 = (wg / NCOLS) * 128, col0 = (wg % NCOLS) * 256;
    const int wm = (w >> 2) * 64, wn = (w & 3) * 64;

    const int ra = t >> 2, sa = ((t & 3) ^ ((ra >> 1) & 3)) * 8;
    const ushort_t* ag = nullptr;
    const float* axr = nullptr;
    if (AMODE == 0) ag = (const ushort_t*)Av + (long)(row0 + ra) * K + sa;
    else            axr = (const float*)Av + swin_src_off(row0 + ra) + sa;

    const int ub0 = t, ub1 = t + 512;
    const int rb0 = ub0 >> 2, sb0 = ((ub0 & 3) ^ ((rb0 >> 1) & 3)) * 8;
    const int rb1 = ub1 >> 2, sb1 = ((ub1 & 3) ^ ((rb1 >> 1) & 3)) * 8;
    const ushort_t* bg0 = W + (long)(col0 + rb0) * K + sb0;
    const ushort_t* bg1 = W + (long)(col0 + rb1) * K + sb1;

    int offA[4], offB[4];
    #pragma unroll
    for (int i = 0; i < 4; i++) {
        int r2 = wm + i * 16 + (lane & 15);
        offA[i] = r2 * 32 + (((lane >> 4) ^ ((r2 >> 1) & 3)) * 8);
        int r3 = wn + i * 16 + (lane & 15);
        offB[i] = r3 * 32 + (((lane >> 4) ^ ((r3 >> 1) & 3)) * 8);
    }

    f32x4 acc[4][4] = {};
    float4 va0, vb0, va1, vb1;

    if (AMODE == 0) {
        gl_lds16(ag,      &As[t * 8]);
        gl_lds16(bg0,      &Bs[ub0 * 8]);
        gl_lds16(bg1,      &Bs[ub1 * 8]);
        gl_lds16(ag + 32, &As[4096 + t * 8]);
        gl_lds16(bg0 + 32, &Bs[8192 + ub0 * 8]);
        gl_lds16(bg1 + 32, &Bs[8192 + ub1 * 8]);
        WAITV3; BAR;
    } else {
        va0 = *(const float4*)axr;        vb0 = *(const float4*)(axr + 4);
        gl_lds16(bg0,      &Bs[ub0 * 8]);
        gl_lds16(bg1,      &Bs[ub1 * 8]);
        va1 = *(const float4*)(axr + 32); vb1 = *(const float4*)(axr + 36);
        gl_lds16(bg0 + 32, &Bs[8192 + ub0 * 8]);
        gl_lds16(bg1 + 32, &Bs[8192 + ub1 * 8]);
        WAITV4;
        *(bf16x8*)&As[t * 8] = pack8(va0, vb0);
        WAITL0; BAR;
    }

    const int nk = K >> 5;
    int i0 = 0, i1 = 1, i2 = 2;
    for (int kt = 0; kt < nk; kt++) {
        const bool more = (kt + 2 < nk);
        if (more) {
            const int k2 = (kt + 2) * 32;
            if (AMODE == 0) {
                gl_lds16(ag + k2, &As[i2 * 4096 + t * 8]);
            } else {
                if (kt & 1) { va1 = *(const float4*)(axr + k2); vb1 = *(const float4*)(axr + k2 + 4); }
                else        { va0 = *(const float4*)(axr + k2); vb0 = *(const float4*)(axr + k2 + 4); }
            }
            gl_lds16(bg0 + k2, &Bs[i2 * 8192 + ub0 * 8]);
            gl_lds16(bg1 + k2, &Bs[i2 * 8192 + ub1 * 8]);
        }
        {
            const int abase = (AMODE == 1 ? (kt & 1) : i0) * 4096;
            const int bbase = i0 * 8192;
            bf16x8 af[4], bw[4];
            #pragma unroll
            for (int i = 0; i < 4; i++) {
                af[i] = *(const bf16x8*)&As[abase + offA[i]];
                bw[i] = *(const bf16x8*)&Bs[bbase + offB[i]];
            }
            PRIO1;
            #pragma unroll
            for (int mi = 0; mi < 4; mi++)
                #pragma unroll
                for (int ni = 0; ni < 4; ni++)
                    acc[mi][ni] = __builtin_amdgcn_mfma_f32_16x16x32_bf16(af[mi], bw[ni], acc[mi][ni], 0, 0, 0);
            PRIO0;
        }
        if (kt < nk - 1) {
            if (AMODE == 0) {
                if (more) { WAITV3; } else { WAITV0; }
            } else {
                if (more) { WAITV4; } else { WAITV0; }
                if (kt & 1) *(bf16x8*)&As[t * 8]        = pack8(va0, vb0);
                else        *(bf16x8*)&As[4096 + t * 8] = pack8(va1, vb1);
                WAITL0;
            }
            BAR;
        }
        int tmp = i0; i0 = i1; i1 = i2; i2 = tmp;
    }

    #pragma unroll
    for (int mi = 0; mi < 4; mi++)
        #pragma unroll
        for (int ni = 0; ni < 4; ni++) {
            const int c = col0 + wn + ni * 16 + (lane & 15);
            const float bv = bias[c];
            #pragma unroll
            for (int r = 0; r < 4; r++) {
                const int rr = row0 + wm + mi * 16 + (lane >> 4) * 4 + r;
                float v = acc[mi][ni][r] + bv;
                if (ACT) v = gelu_f(v);
                C[(long)rr * N + c] = f2bf(v);
            }
        }
}

// ---- gemm128 (r9): 128x128 tile, 256 thr, BK=32 dbuf, ~5 blocks/CU (mlp1) ----
template<int ACT, int NCOLS>
__global__ __launch_bounds__(256)
void gemm128(const ushort_t* __restrict__ A, const ushort_t* __restrict__ W,
             const float* __restrict__ bias, ushort_t* __restrict__ C,
             int M, int N, int K)
{
    __shared__ ushort_t As[2][128 * 32];
    __shared__ ushort_t Bs[2][128 * 32];
    const int t = threadIdx.x, lane = t & 63, wave = t >> 6;
    const int cpx = gridDim.x >> 3;
    const int wg = (blockIdx.x & 7) * cpx + (blockIdx.x >> 3);
    const int row0 = (wg / NCOLS) * 128, col0 = (wg % NCOLS) * 128;
    const int wm = (wave >> 1) * 64, wn = (wave & 1) * 64;

    const int u0 = t, u1 = t + 256;
    const int r0 = u0 >> 2, s0 = ((u0 & 3) ^ ((r0 >> 1) & 3)) * 8;
    const int r1 = u1 >> 2, s1 = ((u1 & 3) ^ ((r1 >> 1) & 3)) * 8;
    const ushort_t* a0 = A + (long)(row0 + r0) * K + s0;
    const ushort_t* a1 = A + (long)(row0 + r1) * K + s1;
    const ushort_t* b0 = W + (long)(col0 + r0) * K + s0;
    const ushort_t* b1 = W + (long)(col0 + r1) * K + s1;

    int offA[4], offB[4];
    #pragma unroll
    for (int i = 0; i < 4; i++) {
        int ra = wm + i * 16 + (lane & 15);
        offA[i] = ra * 32 + (((lane >> 4) ^ ((ra >> 1) & 3)) * 8);
        int rb = wn + i * 16 + (lane & 15);
        offB[i] = rb * 32 + (((lane >> 4) ^ ((rb >> 1) & 3)) * 8);
    }

    f32x4 acc[4][4] = {};
    gl_lds16(a0, &As[0][u0 * 8]); gl_lds16(a1, &As[0][u1 * 8]);
    gl_lds16(b0, &Bs[0][u0 * 8]); gl_lds16(b1, &Bs[0][u1 * 8]);
    WAITV0; BAR;
    const int nk = K >> 5;
    for (int kt = 0; kt < nk - 1; kt++) {
        const int cur = kt & 1, nxt = cur ^ 1, k1 = (kt + 1) * 32;
        gl_lds16(a0 + k1, &As[nxt][u0 * 8]); gl_lds16(a1 + k1, &As[nxt][u1 * 8]);
        gl_lds16(b0 + k1, &Bs[nxt][u0 * 8]); gl_lds16(b1 + k1, &Bs[nxt][u1 * 8]);
        bf16x8 af[4], bw[4];
        #pragma unroll
        for (int i = 0; i < 4; i++) {
            af[i] = *(const bf16x8*)&As[cur][offA[i]];
            bw[i] = *(const bf16x8*)&Bs[cur][offB[i]];
        }
        PRIO1;
        #pragma unroll
        for (int mi = 0; mi < 4; mi++)
            #pragma unroll
            for (int ni = 0; ni < 4; ni++)
                acc[mi][ni] = __builtin_amdgcn_mfma_f32_16x16x32_bf16(af[mi], bw[ni], acc[mi][ni], 0, 0, 0);
        PRIO0;
        WAITV0; BAR;
    }
    {
        const int cur = (nk - 1) & 1;
        bf16x8 af[4], bw[4];
        #pragma unroll
        for (int i = 0; i < 4; i++) {
            af[i] = *(const bf16x8*)&As[cur][offA[i]];
            bw[i] = *(const bf16x8*)&Bs[cur][offB[i]];
        }
        PRIO1;
        #pragma unroll
        for (int mi = 0; mi < 4; mi++)
            #pragma unroll
            for (int ni = 0; ni < 4; ni++)
                acc[mi][ni] = __builtin_amdgcn_mfma_f32_16x16x32_bf16(af[mi], bw[ni], acc[mi][ni], 0, 0, 0);
        PRIO0;
    }
    #pragma unroll
    for (int mi = 0; mi < 4; mi++)
        #pragma unroll
        for (int ni = 0; ni < 4; ni++) {
            const int c = col0 + wn + ni * 16 + (lane & 15);
            const float bv = bias[c];
            #pragma unroll
            for (int r = 0; r < 4; r++) {
                const int rr = row0 + wm + mi * 16 + (lane >> 4) * 4 + r;
                float v = acc[mi][ni][r] + bv;
                if (ACT) v = gelu_f(v);
                C[(long)rr * N + c] = f2bf(v);
            }
        }
}

// ---------------- MFMA attention: one wave per (window, head) ----------------
__global__ __launch_bounds__(64)
void attn_mfma(const ushort_t* __restrict__ qkv, const float* __restrict__ rpb,
               ushort_t* __restrict__ out)
{
    __shared__ ushort_t v_t[32 * 72];    // V^T [d][j], pad 72
    __shared__ ushort_t p_lds[64 * 72];  // P   [i][j], pad 72
    __shared__ float bias_s[169];

    const int blk = blockIdx.x;
    const int n = blk >> 3, h = blk & 7;
    const int l = threadIdx.x;           // 0..63
    const long wbase = (long)n * 49 * 768 + h * 32;
    const float scale = 0.17677669529663687f;   // 32^-0.5

    {
        int j = min(l, 48);
        const ushort_t* vr = qkv + wbase + (long)j * 768 + 512;
        #pragma unroll
        for (int c = 0; c < 4; c++) {
            bf16x8 vv = *(const bf16x8*)(vr + c * 8);
            #pragma unroll
            for (int e = 0; e < 8; e++) v_t[(c * 8 + e) * 72 + l] = (ushort_t)vv[e];
        }
    }
    for (int idx = l; idx < 169; idx += 64) bias_s[idx] = rpb[idx * 8 + h];
    __syncthreads();

    f32x4 s[4][4] = {};
    {
        bf16x8 aq[4], bk[4];
        #pragma unroll
        for (int mt = 0; mt < 4; mt++) {
            int i = min(mt * 16 + (l & 15), 48);
            aq[mt] = *(const bf16x8*)(qkv + wbase + (long)i * 768 + (l >> 4) * 8);
        }
        #pragma unroll
        for (int nt = 0; nt < 4; nt++) {
            int j = min(nt * 16 + (l & 15), 48);
            bk[nt] = *(const bf16x8*)(qkv + wbase + (long)j * 768 + 256 + (l >> 4) * 8);
        }
        #pragma unroll
        for (int mt = 0; mt < 4; mt++)
            #pragma unroll
            for (int nt = 0; nt < 4; nt++)
                s[mt][nt] = __builtin_amdgcn_mfma_f32_16x16x32_bf16(aq[mt], bk[nt], s[mt][nt], 0, 0, 0);
    }

    const int win = n & 63, wh = win >> 3, ww = win & 7;
    int yj[4], xj[4], regj[4]; bool jv[4];
    #pragma unroll
    for (int nt = 0; nt < 4; nt++) {
        int j = nt * 16 + (l & 15);
        jv[nt] = (j <= 48);
        int jc = min(j, 48);
        yj[nt] = jc / 7; xj[nt] = jc - yj[nt] * 7;
        int hs = wh * 7 + yj[nt], wsx = ww * 7 + xj[nt];
        regj[nt] = (hs < 49 ? 0 : (hs < 53 ? 1 : 2)) * 3 + (wsx < 49 ? 0 : (wsx < 53 ? 1 : 2));
    }
    float rinv[4][4];
    #pragma unroll
    for (int mt = 0; mt < 4; mt++) {
        #pragma unroll
        for (int r = 0; r < 4; r++) {
            int i = mt * 16 + (l >> 4) * 4 + r;
            int ic = min(i, 48);
            int yi = ic / 7, xi = ic - yi * 7;
            int hs = wh * 7 + yi, wsx = ww * 7 + xi;
            int regi = (hs < 49 ? 0 : (hs < 53 ? 1 : 2)) * 3 + (wsx < 49 ? 0 : (wsx < 53 ? 1 : 2));
            float val[4];
            #pragma unroll
            for (int nt = 0; nt < 4; nt++) {
                float v = s[mt][nt][r] * scale + bias_s[(yi - yj[nt] + 6) * 13 + (xi - xj[nt] + 6)];
                if (regi != regj[nt]) v -= 100.f;
                val[nt] = jv[nt] ? v : -1e30f;
            }
            float mx = fmaxf(fmaxf(val[0], val[1]), fmaxf(val[2], val[3]));
            #pragma unroll
            for (int off = 1; off <= 8; off <<= 1) mx = fmaxf(mx, __shfl_xor(mx, off));
            float sum = 0.f;
            #pragma unroll
            for (int nt = 0; nt < 4; nt++) { val[nt] = __expf(val[nt] - mx); sum += val[nt]; }
            #pragma unroll
            for (int off = 1; off <= 8; off <<= 1) sum += __shfl_xor(sum, off);
            rinv[mt][r] = 1.0f / sum;
            #pragma unroll
            for (int nt = 0; nt < 4; nt++)
                p_lds[i * 72 + nt * 16 + (l & 15)] = f2bf(val[nt]);
        }
    }
    __syncthreads();

    f32x4 o[4][2] = {};
    #pragma unroll
    for (int ks = 0; ks < 2; ks++) {
        bf16x8 pa[4], vb[2];
        #pragma unroll
        for (int mt = 0; mt < 4; mt++)
            pa[mt] = *(const bf16x8*)&p_lds[(mt * 16 + (l & 15)) * 72 + ks * 32 + (l >> 4) * 8];
        #pragma unroll
        for (int nt = 0; nt < 2; nt++)
            vb[nt] = *(const bf16x8*)&v_t[(nt * 16 + (l & 15)) * 72 + ks * 32 + (l >> 4) * 8];
        #pragma unroll
        for (int mt = 0; mt < 4; mt++)
            #pragma unroll
            for (int nt = 0; nt < 2; nt++)
                o[mt][nt] = __builtin_amdgcn_mfma_f32_16x16x32_bf16(pa[mt], vb[nt], o[mt][nt], 0, 0, 0);
    }
    #pragma unroll
    for (int mt = 0; mt < 4; mt++)
        #pragma unroll
        for (int r = 0; r < 4; r++) {
            int i = mt * 16 + (l >> 4) * 4 + r;
            if (i < 49) {
                float rs = rinv[mt][r];
                #pragma unroll
                for (int nt = 0; nt < 2; nt++) {
                    int d = nt * 16 + (l & 15);
                    out[((long)n * 49 + i) * 256 + h * 32 + d] = f2bf(o[mt][nt][r] * rs);
                }
            }
        }
}

// ------- projln1: 128x256 3-deep GEMM + LN1 + residual -> x1 bf16 (512 thr) -------
__global__ __launch_bounds__(512)
void projln1(const ushort_t* __restrict__ A, const ushort_t* __restrict__ W,
             const float* __restrict__ pb, const float* __restrict__ x,
             const float* __restrict__ gamma, const float* __restrict__ beta,
             ushort_t* __restrict__ x1b)
{
    __shared__ ushort_t As[3 * 4096];
    __shared__ ushort_t Bs[3 * 8192];
    __shared__ float red_s[128][4];
    __shared__ float red_ss[128][4];
    __shared__ int srow_s[128];
    const int t = threadIdx.x, lane = t & 63, w = t >> 6;
    const int row0 = blockIdx.x * 128;
    const int wm = (w >> 2) * 64, wn = (w & 3) * 64;

    if (t < 128) srow_s[t] = (int)(swin_src_off(row0 + t) >> 8);

    const int ra0 = t >> 2, sa0 = ((t & 3) ^ ((ra0 >> 1) & 3)) * 8;
    const ushort_t* ag = A + (long)(row0 + ra0) * 256 + sa0;
    const int ub0 = t, ub1 = t + 512;
    const int rb0 = ub0 >> 2, sb0 = ((ub0 & 3) ^ ((rb0 >> 1) & 3)) * 8;
    const int rb1 = ub1 >> 2, sb1 = ((ub1 & 3) ^ ((rb1 >> 1) & 3)) * 8;
    const ushort_t* bg0 = W + (long)rb0 * 256 + sb0;
    const ushort_t* bg1 = W + (long)rb1 * 256 + sb1;

    int offA[4], offB[4];
    #pragma unroll
    for (int i = 0; i < 4; i++) {
        int ra = wm + i * 16 + (lane & 15);
        offA[i] = ra * 32 + (((lane >> 4) ^ ((ra >> 1) & 3)) * 8);
        int rb = wn + i * 16 + (lane & 15);
        offB[i] = rb * 32 + (((lane >> 4) ^ ((rb >> 1) & 3)) * 8);
    }

    f32x4 acc[4][4] = {};
    gl_lds16(ag,       &As[t * 8]);
    gl_lds16(bg0,       &Bs[ub0 * 8]);
    gl_lds16(bg1,       &Bs[ub1 * 8]);
    gl_lds16(ag + 32,  &As[4096 + t * 8]);
    gl_lds16(bg0 + 32,  &Bs[8192 + ub0 * 8]);
    gl_lds16(bg1 + 32,  &Bs[8192 + ub1 * 8]);
    WAITV3; BAR;

    int i0 = 0, i1 = 1, i2 = 2;
    for (int kt = 0; kt < 8; kt++) {
        const bool more = (kt + 2 < 8);
        if (more) {
            const int k2 = (kt + 2) * 32;
            gl_lds16(ag + k2, &As[i2 * 4096 + t * 8]);
            gl_lds16(bg0 + k2, &Bs[i2 * 8192 + ub0 * 8]);
            gl_lds16(bg1 + k2, &Bs[i2 * 8192 + ub1 * 8]);
        }
        bf16x8 af[4], bw[4];
        #pragma unroll
        for (int i = 0; i < 4; i++) {
            af[i] = *(const bf16x8*)&As[i0 * 4096 + offA[i]];
            bw[i] = *(const bf16x8*)&Bs[i0 * 8192 + offB[i]];
        }
        PRIO1;
        #pragma unroll
        for (int mi = 0; mi < 4; mi++)
            #pragma unroll
            for (int ni = 0; ni < 4; ni++)
                acc[mi][ni] = __builtin_amdgcn_mfma_f32_16x16x32_bf16(af[mi], bw[ni], acc[mi][ni], 0, 0, 0);
        PRIO0;
        if (kt < 7) {
            if (more) { WAITV3; } else { WAITV0; }
            BAR;
        }
        int tmp = i0; i0 = i1; i1 = i2; i2 = tmp;
    }

    float pbv[4], g1v[4], be1v[4];
    #pragma unroll
    for (int ni = 0; ni < 4; ni++) {
        int col = wn + ni * 16 + (lane & 15);
        pbv[ni] = pb[col]; g1v[ni] = gamma[col]; be1v[ni] = beta[col];
    }
    #pragma unroll
    for (int mi = 0; mi < 4; mi++)
        #pragma unroll
        for (int rr = 0; rr < 4; rr++) {
            float s = 0.f, ss = 0.f;
            #pragma unroll
            for (int ni = 0; ni < 4; ni++) {
                float v = acc[mi][ni][rr] + pbv[ni];
                acc[mi][ni][rr] = v; s += v; ss += v * v;
            }
            #pragma unroll
            for (int off = 1; off <= 8; off <<= 1) { s += __shfl_xor(s, off); ss += __shfl_xor(ss, off); }
            if ((lane & 15) == 0) {
                int r = wm + mi * 16 + (lane >> 4) * 4 + rr;
                red_s[r][w & 3] = s; red_ss[r][w & 3] = ss;
            }
        }
    __syncthreads();
    #pragma unroll
    for (int mi = 0; mi < 4; mi++)
        #pragma unroll
        for (int rr = 0; rr < 4; rr++) {
            const int r = wm + mi * 16 + (lane >> 4) * 4 + rr;
            const float s = red_s[r][0] + red_s[r][1] + red_s[r][2] + red_s[r][3];
            const float ss = red_ss[r][0] + red_ss[r][1] + red_ss[r][2] + red_ss[r][3];
            const float mu = s * (1.0f / 256.0f);
            const float rstd = rsqrtf(ss * (1.0f / 256.0f) - mu * mu + 1e-5f);
            const long sp = srow_s[r];
            #pragma unroll
            for (int ni = 0; ni < 4; ni++) {
                int col = wn + ni * 16 + (lane & 15);
                float o = x[sp * 256 + col] + (acc[mi][ni][rr] - mu) * rstd * g1v[ni] + be1v[ni];
                x1b[sp * 256 + col] = f2bf(o);
            }
        }
}

// ------- mlp2ln2 (r9 geometry): 64x256 dbuf GEMM (K=1024) + LN2 + residual -------
__global__ __launch_bounds__(256)
void mlp2ln2(const ushort_t* __restrict__ A, const ushort_t* __restrict__ W,
             const float* __restrict__ pb, const ushort_t* __restrict__ x1res,
             const float* __restrict__ gamma, const float* __restrict__ beta,
             float* __restrict__ out)
{
    __shared__ ushort_t As[2][64 * 32];
    __shared__ ushort_t Bs[2][256 * 32];
    __shared__ float red_s[64][4];
    __shared__ float red_ss[64][4];
    const int t = threadIdx.x, lane = t & 63, w = t >> 6;
    const int row0 = blockIdx.x * 64;
    const int wn = w * 64;

    const int ra0 = t >> 2, sa0 = ((t & 3) ^ ((ra0 >> 1) & 3)) * 8;
    const ushort_t* ag = A + (long)(row0 + ra0) * 1024 + sa0;
    const ushort_t* bg[4];
    int ub[4];
    #pragma unroll
    for (int i = 0; i < 4; i++) {
        ub[i] = t + i * 256;
        int rb = ub[i] >> 2, sb = ((ub[i] & 3) ^ ((rb >> 1) & 3)) * 8;
        bg[i] = W + (long)rb * 1024 + sb;
    }

    int offA[4], offB[4];
    #pragma unroll
    for (int i = 0; i < 4; i++) {
        int ra = i * 16 + (lane & 15);
        offA[i] = ra * 32 + (((lane >> 4) ^ ((ra >> 1) & 3)) * 8);
        int rb = wn + i * 16 + (lane & 15);
        offB[i] = rb * 32 + (((lane >> 4) ^ ((rb >> 1) & 3)) * 8);
    }

    f32x4 acc[4][4] = {};
    gl_lds16(ag, &As[0][t * 8]);
    #pragma unroll
    for (int i = 0; i < 4; i++) gl_lds16(bg[i], &Bs[0][ub[i] * 8]);
    WAITV0; BAR;
    for (int kt = 0; kt < 31; kt++) {
        const int cur = kt & 1, nxt = cur ^ 1, k1 = (kt + 1) * 32;
        gl_lds16(ag + k1, &As[nxt][t * 8]);
        #pragma unroll
        for (int i = 0; i < 4; i++) gl_lds16(bg[i] + k1, &Bs[nxt][ub[i] * 8]);
        bf16x8 af[4], bw[4];
        #pragma unroll
        for (int i2 = 0; i2 < 4; i2++) {
            af[i2] = *(const bf16x8*)&As[cur][offA[i2]];
            bw[i2] = *(const bf16x8*)&Bs[cur][offB[i2]];
        }
        PRIO1;
        #pragma unroll
        for (int mi = 0; mi < 4; mi++)
            #pragma unroll
            for (int ni = 0; ni < 4; ni++)
                acc[mi][ni] = __builtin_amdgcn_mfma_f32_16x16x32_bf16(af[mi], bw[ni], acc[mi][ni], 0, 0, 0);
        PRIO0;
        WAITV0; BAR;
    }
    {
        bf16x8 af[4], bw[4];
        #pragma unroll
        for (int i2 = 0; i2 < 4; i2++) {
            af[i2] = *(const bf16x8*)&As[1][offA[i2]];
            bw[i2] = *(const bf16x8*)&Bs[1][offB[i2]];
        }
        PRIO1;
        #pragma unroll
        for (int mi = 0; mi < 4; mi++)
            #pragma unroll
            for (int ni = 0; ni < 4; ni++)
                acc[mi][ni] = __builtin_amdgcn_mfma_f32_16x16x32_bf16(af[mi], bw[ni], acc[mi][ni], 0, 0, 0);
        PRIO0;
    }
    float pbv[4], g2v[4], be2v[4];
    #pragma unroll
    for (int ni = 0; ni < 4; ni++) {
        int col = wn + ni * 16 + (lane & 15);
        pbv[ni] = pb[col]; g2v[ni] = gamma[col]; be2v[ni] = beta[col];
    }
    #pragma unroll
    for (int mi = 0; mi < 4; mi++)
        #pragma unroll
        for (int rr = 0; rr < 4; rr++) {
            float s = 0.f, ss = 0.f;
            #pragma unroll
            for (int ni = 0; ni < 4; ni++) {
                float v = acc[mi][ni][rr] + pbv[ni];
                acc[mi][ni][rr] = v; s += v; ss += v * v;
            }
            #pragma unroll
            for (int off = 1; off <= 8; off <<= 1) { s += __shfl_xor(s, off); ss += __shfl_xor(ss, off); }
            if ((lane & 15) == 0) {
                int r = mi * 16 + (lane >> 4) * 4 + rr;
                red_s[r][w] = s; red_ss[r][w] = ss;
            }
        }
    __syncthreads();
    #pragma unroll
    for (int mi = 0; mi < 4; mi++)
        #pragma unroll
        for (int rr = 0; rr < 4; rr++) {
            const int r = mi * 16 + (lane >> 4) * 4 + rr;
            const float s = red_s[r][0] + red_s[r][1] + red_s[r][2] + red_s[r][3];
            const float ss = red_ss[r][0] + red_ss[r][1] + red_ss[r][2] + red_ss[r][3];
            const float mu = s * (1.0f / 256.0f);
            const float rstd = rsqrtf(ss * (1.0f / 256.0f) - mu * mu + 1e-5f);
            const long gr = row0 + r;
            #pragma unroll
            for (int ni = 0; ni < 4; ni++) {
                int col = wn + ni * 16 + (lane & 15);
                out[gr * 256 + col] = bf2f(x1res[gr * 256 + col])
                                    + (acc[mi][ni][rr] - mu) * rstd * g2v[ni] + be2v[ni];
            }
        }
}

extern "C" void kernel_launch(void* const* d_in, const int* in_sizes, int n_in,
                              void* d_out, int out_size, void* d_ws, size_t ws_size,
                              hipStream_t stream) {
    const float* x      = (const float*)d_in[0];
    const float* qkv_w  = (const float*)d_in[1];
    const float* qkv_b  = (const float*)d_in[2];
    const float* proj_w = (const float*)d_in[3];
    const float* proj_b = (const float*)d_in[4];
    const float* rpb    = (const float*)d_in[5];
    const float* gamma1 = (const float*)d_in[6];
    const float* beta1  = (const float*)d_in[7];
    const float* w1     = (const float*)d_in[8];
    const float* b1     = (const float*)d_in[9];
    const float* w2     = (const float*)d_in[10];
    const float* b2     = (const float*)d_in[11];
    const float* gamma2 = (const float*)d_in[12];
    const float* beta2  = (const float*)d_in[13];
    float* outf = (float*)d_out;

    // d_out[0,51.4M) holds attnout (bf16) until projln1 consumes it.
    ushort_t* attnout = (ushort_t*)d_out;

    char* ws = (char*)d_ws;
    ushort_t* qkvb  = (ushort_t*)ws;                      // [0,154.1M)   qkv -> attn (dead after)
    ushort_t* x1b   = (ushort_t*)ws;                      // [0,51.4M)    projln1 -> MLP (qkvb dead)
    ushort_t* hbuf  = (ushort_t*)(ws + 51380224ULL);      // [51.4,256.9M) full-M hidden
    ushort_t* wqkvb = (ushort_t*)(ws + 256901120ULL);     // bf16 weights [N][K]
    ushort_t* wprojb= (ushort_t*)(ws + 257294336ULL);
    ushort_t* w1t   = (ushort_t*)(ws + 257425408ULL);
    ushort_t* w2t   = (ushort_t*)(ws + 257949696ULL);

    const int M = 100352;
    dim3 blk(256);
    // prep: all bf16 weights in one dispatch
    convAll<<<dim3(3072), blk, 0, stream>>>(qkv_w, proj_w, w1, w2,
                                            wqkvb, wprojb, w1t, w2t);
    // 1. qkv = gather(x) @ Wqkv^T + b  (128x256 tile, fused gather, NCOLS=3)
    gemmW<0, 1, 3><<<dim3(2352), dim3(512), 0, stream>>>(x, wqkvb, qkv_b, qkvb, M, 768, 256);
    // 2. windowed attention
    attn_mfma<<<dim3(16384), dim3(64), 0, stream>>>(qkvb, rpb, attnout);
    // 3. proj + LN1 + residual -> x1 bf16 (scattered to natural row order)
    projln1<<<dim3(784), dim3(512), 0, stream>>>(attnout, wprojb, proj_b, x,
                                                 gamma1, beta1, x1b);
    // 4. h = gelu(x1 @ W1^T + b1): 128x128 small-block GEMM, ~5 blocks/CU
    gemm128<1, 8><<<dim3(6272), blk, 0, stream>>>(x1b, w1t, b1, hbuf, M, 1024, 256);
    // 5. out = x1 + LN2(h @ W2^T + b2): 64x256 small-block, 3 blocks/CU
    mlp2ln2<<<dim3(1568), blk, 0, stream>>>(hbuf, w2t, b2, x1b,
                                            gamma2, beta2, outf);
}

// Round 16
// 510.311 us; speedup vs baseline: 1.0326x; 1.0326x over previous
//
#include <hip/hip_runtime.h>
#include <hip/hip_bf16.h>

// SwinBlock r16: r14 (best, 520us) + merged convAll prep (4 launches -> 1).
// GEMMs: 3-deep counted-vmcnt 2-phase loops + k-slot swizzle (conflicts=0) +
// setprio; qkv fuses the shifted-window gather. Structural ceiling of this
// class measured at ~320-350 TF/GEMM across 7 variants (r9-r15).
// B=32 H=W=56 C=256 NH=8 HD=32 WS=7 SS=3 L=49 nWin=64 -> 2048 windows, M=100352.

typedef unsigned short ushort_t;
typedef short bf16x8 __attribute__((ext_vector_type(8)));
typedef float f32x4 __attribute__((ext_vector_type(4)));

#define WAITV0 asm volatile("s_waitcnt vmcnt(0)" ::: "memory")
#define WAITV3 asm volatile("s_waitcnt vmcnt(3)" ::: "memory")
#define WAITV4 asm volatile("s_waitcnt vmcnt(4)" ::: "memory")
#define WAITL0 asm volatile("s_waitcnt lgkmcnt(0)" ::: "memory")
#define BAR    __builtin_amdgcn_s_barrier()
#define PRIO1  __builtin_amdgcn_s_setprio(1)
#define PRIO0  __builtin_amdgcn_s_setprio(0)

__device__ __forceinline__ float bf2f(unsigned short u) {
    union { unsigned int i; float f; } x; x.i = ((unsigned int)u) << 16; return x.f;
}
__device__ __forceinline__ unsigned short f2bf(float f) {
    union { float f; unsigned int i; } x; x.f = f;
    unsigned int r = x.i + 0x7fffu + ((x.i >> 16) & 1u);   // RNE
    return (unsigned short)(r >> 16);
}
__device__ __forceinline__ bf16x8 pack8(float4 a, float4 b) {
    bf16x8 r;
    r[0] = (short)f2bf(a.x); r[1] = (short)f2bf(a.y);
    r[2] = (short)f2bf(a.z); r[3] = (short)f2bf(a.w);
    r[4] = (short)f2bf(b.x); r[5] = (short)f2bf(b.y);
    r[6] = (short)f2bf(b.z); r[7] = (short)f2bf(b.w);
    return r;
}
__device__ __forceinline__ void gl_lds16(const ushort_t* g, ushort_t* l) {
    __builtin_amdgcn_global_load_lds((const __attribute__((address_space(1))) void*)g,
                                     (__attribute__((address_space(3))) void*)l, 16, 0, 0);
}
// exact-erf GELU via Abramowitz-Stegun 7.1.26 (max |err| 1.5e-7)
__device__ __forceinline__ float gelu_f(float v) {
    float s = v * 0.70710678118654752f;
    float ax = fabsf(s);
    float t = __builtin_amdgcn_rcpf(1.0f + 0.3275911f * ax);
    float poly = ((((1.061405429f * t - 1.453152027f) * t + 1.421413741f) * t
                   - 0.284496736f) * t + 0.254829592f) * t;
    float y = 1.0f - poly * __expf(-ax * ax);
    float e = (s < 0.f) ? -y : y;
    return 0.5f * v * (1.0f + e);
}

// row m of the windowed/shifted activation -> element offset into x[B,H,W,C]
__device__ __forceinline__ long swin_src_off(int m) {
    int n = m / 49, l = m - n * 49;
    int b = n >> 6, win = n & 63;
    int wh = win >> 3, ww = win & 7;
    int i = l / 7, j = l - i * 7;
    int hs = wh * 7 + i + 3; if (hs >= 56) hs -= 56;   // roll(-3)
    int ws = ww * 7 + j + 3; if (ws >= 56) ws -= 56;
    return ((long)(b * 56 + hs) * 56 + ws) * 256;
}

// ------- prep: all four weights fp32 -> bf16 [N][K] in ONE dispatch -------
__global__ __launch_bounds__(256)
void convAll(const float* __restrict__ qkv_w, const float* __restrict__ proj_w,
             const float* __restrict__ w1, const float* __restrict__ w2,
             ushort_t* __restrict__ dq, ushort_t* __restrict__ dp,
             ushort_t* __restrict__ d1, ushort_t* __restrict__ d2)
{
    int b = blockIdx.x, tix = threadIdx.x;
    if (b < 768) {
        int idx = b * 256 + tix;
        dq[idx] = f2bf(qkv_w[idx]);
    } else if (b < 1024) {
        int idx = (b - 768) * 256 + tix;
        dp[idx] = f2bf(proj_w[idx]);
    } else if (b < 2048) {
        int idx = (b - 1024) * 256 + tix;
        int kk = idx & 255, nn = idx >> 8;           // d1[nn][kk] = w1[kk][nn]
        d1[idx] = f2bf(w1[(long)kk * 1024 + nn]);
    } else {
        int idx = (b - 2048) * 256 + tix;
        int kk = idx & 1023, nn = idx >> 10;         // d2[nn][kk] = w2[kk][nn]
        d2[idx] = f2bf(w2[(long)kk * 256 + nn]);
    }
}

// ---- gemmW: 128x256 tile, 512 thr / 8 waves, BK=32, 3-deep counted-vmcnt loop ----
template<int ACT, int AMODE, int NCOLS>
__global__ __launch_bounds__(512)
void gemmW(const void* __restrict__ Av, const ushort_t* __restrict__ W,
           const float* __restrict__ bias, ushort_t* __restrict__ C,
           int M, int N, int K)
{
    constexpr int NA = (AMODE == 1) ? 2 : 3;
    __shared__ ushort_t As[NA * 4096];
    __shared__ ushort_t Bs[3 * 8192];
    const int t = threadIdx.x, lane = t & 63, w = t >> 6;
    const int cpx = gridDim.x >> 3;
    const int wg = (blockIdx.x & 7) * cpx + (blockIdx.x >> 3);
    const int row0 = (wg / NCOLS) * 128, col0 = (wg % NCOLS) * 256;
    const int wm = (w >> 2) * 64, wn = (w & 3) * 64;

    const int ra = t >> 2, sa = ((t & 3) ^ ((ra >> 1) & 3)) * 8;
    const ushort_t* ag = nullptr;
    const float* axr = nullptr;
    if (AMODE == 0) ag = (const ushort_t*)Av + (long)(row0 + ra) * K + sa;
    else            axr = (const float*)Av + swin_src_off(row0 + ra) + sa;

    const int ub0 = t, ub1 = t + 512;
    const int rb0 = ub0 >> 2, sb0 = ((ub0 & 3) ^ ((rb0 >> 1) & 3)) * 8;
    const int rb1 = ub1 >> 2, sb1 = ((ub1 & 3) ^ ((rb1 >> 1) & 3)) * 8;
    const ushort_t* bg0 = W + (long)(col0 + rb0) * K + sb0;
    const ushort_t* bg1 = W + (long)(col0 + rb1) * K + sb1;

    int offA[4], offB[4];
    #pragma unroll
    for (int i = 0; i < 4; i++) {
        int r2 = wm + i * 16 + (lane & 15);
        offA[i] = r2 * 32 + (((lane >> 4) ^ ((r2 >> 1) & 3)) * 8);
        int r3 = wn + i * 16 + (lane & 15);
        offB[i] = r3 * 32 + (((lane >> 4) ^ ((r3 >> 1) & 3)) * 8);
    }

    f32x4 acc[4][4] = {};
    float4 va0, vb0, va1, vb1;           // AMODE1: A(j) lives in set j&1

    if (AMODE == 0) {
        gl_lds16(ag,      &As[t * 8]);
        gl_lds16(bg0,      &Bs[ub0 * 8]);
        gl_lds16(bg1,      &Bs[ub1 * 8]);
        gl_lds16(ag + 32, &As[4096 + t * 8]);
        gl_lds16(bg0 + 32, &Bs[8192 + ub0 * 8]);
        gl_lds16(bg1 + 32, &Bs[8192 + ub1 * 8]);
        WAITV3; BAR;
    } else {
        va0 = *(const float4*)axr;        vb0 = *(const float4*)(axr + 4);
        gl_lds16(bg0,      &Bs[ub0 * 8]);
        gl_lds16(bg1,      &Bs[ub1 * 8]);
        va1 = *(const float4*)(axr + 32); vb1 = *(const float4*)(axr + 36);
        gl_lds16(bg0 + 32, &Bs[8192 + ub0 * 8]);
        gl_lds16(bg1 + 32, &Bs[8192 + ub1 * 8]);
        WAITV4;
        *(bf16x8*)&As[t * 8] = pack8(va0, vb0);
        WAITL0; BAR;
    }

    const int nk = K >> 5;
    int i0 = 0, i1 = 1, i2 = 2;
    for (int kt = 0; kt < nk; kt++) {
        const bool more = (kt + 2 < nk);
        if (more) {
            const int k2 = (kt + 2) * 32;
            if (AMODE == 0) {
                gl_lds16(ag + k2, &As[i2 * 4096 + t * 8]);
            } else {
                if (kt & 1) { va1 = *(const float4*)(axr + k2); vb1 = *(const float4*)(axr + k2 + 4); }
                else        { va0 = *(const float4*)(axr + k2); vb0 = *(const float4*)(axr + k2 + 4); }
            }
            gl_lds16(bg0 + k2, &Bs[i2 * 8192 + ub0 * 8]);
            gl_lds16(bg1 + k2, &Bs[i2 * 8192 + ub1 * 8]);
        }
        {
            const int abase = (AMODE == 1 ? (kt & 1) : i0) * 4096;
            const int bbase = i0 * 8192;
            bf16x8 af[4], bw[4];
            #pragma unroll
            for (int i = 0; i < 4; i++) {
                af[i] = *(const bf16x8*)&As[abase + offA[i]];
                bw[i] = *(const bf16x8*)&Bs[bbase + offB[i]];
            }
            PRIO1;
            #pragma unroll
            for (int mi = 0; mi < 4; mi++)
                #pragma unroll
                for (int ni = 0; ni < 4; ni++)
                    acc[mi][ni] = __builtin_amdgcn_mfma_f32_16x16x32_bf16(af[mi], bw[ni], acc[mi][ni], 0, 0, 0);
            PRIO0;
        }
        if (kt < nk - 1) {
            if (AMODE == 0) {
                if (more) { WAITV3; } else { WAITV0; }
            } else {
                if (more) { WAITV4; } else { WAITV0; }
                if (kt & 1) *(bf16x8*)&As[t * 8]        = pack8(va0, vb0);
                else        *(bf16x8*)&As[4096 + t * 8] = pack8(va1, vb1);
                WAITL0;
            }
            BAR;
        }
        int tmp = i0; i0 = i1; i1 = i2; i2 = tmp;
    }

    #pragma unroll
    for (int mi = 0; mi < 4; mi++)
        #pragma unroll
        for (int ni = 0; ni < 4; ni++) {
            const int c = col0 + wn + ni * 16 + (lane & 15);
            const float bv = bias[c];
            #pragma unroll
            for (int r = 0; r < 4; r++) {
                const int rr = row0 + wm + mi * 16 + (lane >> 4) * 4 + r;
                float v = acc[mi][ni][r] + bv;
                if (ACT) v = gelu_f(v);
                C[(long)rr * N + c] = f2bf(v);
            }
        }
}

// ---------------- MFMA attention: one wave per (window, head) ----------------
__global__ __launch_bounds__(64)
void attn_mfma(const ushort_t* __restrict__ qkv, const float* __restrict__ rpb,
               ushort_t* __restrict__ out)
{
    __shared__ ushort_t v_t[32 * 72];    // V^T [d][j], pad 72
    __shared__ ushort_t p_lds[64 * 72];  // P   [i][j], pad 72
    __shared__ float bias_s[169];

    const int blk = blockIdx.x;
    const int n = blk >> 3, h = blk & 7;
    const int l = threadIdx.x;           // 0..63
    const long wbase = (long)n * 49 * 768 + h * 32;
    const float scale = 0.17677669529663687f;   // 32^-0.5

    {
        int j = min(l, 48);
        const ushort_t* vr = qkv + wbase + (long)j * 768 + 512;
        #pragma unroll
        for (int c = 0; c < 4; c++) {
            bf16x8 vv = *(const bf16x8*)(vr + c * 8);
            #pragma unroll
            for (int e = 0; e < 8; e++) v_t[(c * 8 + e) * 72 + l] = (ushort_t)vv[e];
        }
    }
    for (int idx = l; idx < 169; idx += 64) bias_s[idx] = rpb[idx * 8 + h];
    __syncthreads();

    f32x4 s[4][4] = {};
    {
        bf16x8 aq[4], bk[4];
        #pragma unroll
        for (int mt = 0; mt < 4; mt++) {
            int i = min(mt * 16 + (l & 15), 48);
            aq[mt] = *(const bf16x8*)(qkv + wbase + (long)i * 768 + (l >> 4) * 8);
        }
        #pragma unroll
        for (int nt = 0; nt < 4; nt++) {
            int j = min(nt * 16 + (l & 15), 48);
            bk[nt] = *(const bf16x8*)(qkv + wbase + (long)j * 768 + 256 + (l >> 4) * 8);
        }
        #pragma unroll
        for (int mt = 0; mt < 4; mt++)
            #pragma unroll
            for (int nt = 0; nt < 4; nt++)
                s[mt][nt] = __builtin_amdgcn_mfma_f32_16x16x32_bf16(aq[mt], bk[nt], s[mt][nt], 0, 0, 0);
    }

    const int win = n & 63, wh = win >> 3, ww = win & 7;
    int yj[4], xj[4], regj[4]; bool jv[4];
    #pragma unroll
    for (int nt = 0; nt < 4; nt++) {
        int j = nt * 16 + (l & 15);
        jv[nt] = (j <= 48);
        int jc = min(j, 48);
        yj[nt] = jc / 7; xj[nt] = jc - yj[nt] * 7;
        int hs = wh * 7 + yj[nt], wsx = ww * 7 + xj[nt];
        regj[nt] = (hs < 49 ? 0 : (hs < 53 ? 1 : 2)) * 3 + (wsx < 49 ? 0 : (wsx < 53 ? 1 : 2));
    }
    float rinv[4][4];
    #pragma unroll
    for (int mt = 0; mt < 4; mt++) {
        #pragma unroll
        for (int r = 0; r < 4; r++) {
            int i = mt * 16 + (l >> 4) * 4 + r;
            int ic = min(i, 48);
            int yi = ic / 7, xi = ic - yi * 7;
            int hs = wh * 7 + yi, wsx = ww * 7 + xi;
            int regi = (hs < 49 ? 0 : (hs < 53 ? 1 : 2)) * 3 + (wsx < 49 ? 0 : (wsx < 53 ? 1 : 2));
            float val[4];
            #pragma unroll
            for (int nt = 0; nt < 4; nt++) {
                float v = s[mt][nt][r] * scale + bias_s[(yi - yj[nt] + 6) * 13 + (xi - xj[nt] + 6)];
                if (regi != regj[nt]) v -= 100.f;
                val[nt] = jv[nt] ? v : -1e30f;
            }
            float mx = fmaxf(fmaxf(val[0], val[1]), fmaxf(val[2], val[3]));
            #pragma unroll
            for (int off = 1; off <= 8; off <<= 1) mx = fmaxf(mx, __shfl_xor(mx, off));
            float sum = 0.f;
            #pragma unroll
            for (int nt = 0; nt < 4; nt++) { val[nt] = __expf(val[nt] - mx); sum += val[nt]; }
            #pragma unroll
            for (int off = 1; off <= 8; off <<= 1) sum += __shfl_xor(sum, off);
            rinv[mt][r] = 1.0f / sum;
            #pragma unroll
            for (int nt = 0; nt < 4; nt++)
                p_lds[i * 72 + nt * 16 + (l & 15)] = f2bf(val[nt]);
        }
    }
    __syncthreads();

    f32x4 o[4][2] = {};
    #pragma unroll
    for (int ks = 0; ks < 2; ks++) {
        bf16x8 pa[4], vb[2];
        #pragma unroll
        for (int mt = 0; mt < 4; mt++)
            pa[mt] = *(const bf16x8*)&p_lds[(mt * 16 + (l & 15)) * 72 + ks * 32 + (l >> 4) * 8];
        #pragma unroll
        for (int nt = 0; nt < 2; nt++)
            vb[nt] = *(const bf16x8*)&v_t[(nt * 16 + (l & 15)) * 72 + ks * 32 + (l >> 4) * 8];
        #pragma unroll
        for (int mt = 0; mt < 4; mt++)
            #pragma unroll
            for (int nt = 0; nt < 2; nt++)
                o[mt][nt] = __builtin_amdgcn_mfma_f32_16x16x32_bf16(pa[mt], vb[nt], o[mt][nt], 0, 0, 0);
    }
    #pragma unroll
    for (int mt = 0; mt < 4; mt++)
        #pragma unroll
        for (int r = 0; r < 4; r++) {
            int i = mt * 16 + (l >> 4) * 4 + r;
            if (i < 49) {
                float rs = rinv[mt][r];
                #pragma unroll
                for (int nt = 0; nt < 2; nt++) {
                    int d = nt * 16 + (l & 15);
                    out[((long)n * 49 + i) * 256 + h * 32 + d] = f2bf(o[mt][nt][r] * rs);
                }
            }
        }
}

// ------- projln1: 128x256 3-deep GEMM + LN1 + residual -> x1 bf16 (512 thr) -------
__global__ __launch_bounds__(512)
void projln1(const ushort_t* __restrict__ A, const ushort_t* __restrict__ W,
             const float* __restrict__ pb, const float* __restrict__ x,
             const float* __restrict__ gamma, const float* __restrict__ beta,
             ushort_t* __restrict__ x1b)
{
    __shared__ ushort_t As[3 * 4096];
    __shared__ ushort_t Bs[3 * 8192];
    __shared__ float red_s[128][4];
    __shared__ float red_ss[128][4];
    __shared__ int srow_s[128];
    const int t = threadIdx.x, lane = t & 63, w = t >> 6;
    const int row0 = blockIdx.x * 128;
    const int wm = (w >> 2) * 64, wn = (w & 3) * 64;

    if (t < 128) srow_s[t] = (int)(swin_src_off(row0 + t) >> 8);

    const int ra0 = t >> 2, sa0 = ((t & 3) ^ ((ra0 >> 1) & 3)) * 8;
    const ushort_t* ag = A + (long)(row0 + ra0) * 256 + sa0;
    const int ub0 = t, ub1 = t + 512;
    const int rb0 = ub0 >> 2, sb0 = ((ub0 & 3) ^ ((rb0 >> 1) & 3)) * 8;
    const int rb1 = ub1 >> 2, sb1 = ((ub1 & 3) ^ ((rb1 >> 1) & 3)) * 8;
    const ushort_t* bg0 = W + (long)rb0 * 256 + sb0;
    const ushort_t* bg1 = W + (long)rb1 * 256 + sb1;

    int offA[4], offB[4];
    #pragma unroll
    for (int i = 0; i < 4; i++) {
        int ra = wm + i * 16 + (lane & 15);
        offA[i] = ra * 32 + (((lane >> 4) ^ ((ra >> 1) & 3)) * 8);
        int rb = wn + i * 16 + (lane & 15);
        offB[i] = rb * 32 + (((lane >> 4) ^ ((rb >> 1) & 3)) * 8);
    }

    f32x4 acc[4][4] = {};
    gl_lds16(ag,       &As[t * 8]);
    gl_lds16(bg0,       &Bs[ub0 * 8]);
    gl_lds16(bg1,       &Bs[ub1 * 8]);
    gl_lds16(ag + 32,  &As[4096 + t * 8]);
    gl_lds16(bg0 + 32,  &Bs[8192 + ub0 * 8]);
    gl_lds16(bg1 + 32,  &Bs[8192 + ub1 * 8]);
    WAITV3; BAR;

    int i0 = 0, i1 = 1, i2 = 2;
    for (int kt = 0; kt < 8; kt++) {
        const bool more = (kt + 2 < 8);
        if (more) {
            const int k2 = (kt + 2) * 32;
            gl_lds16(ag + k2, &As[i2 * 4096 + t * 8]);
            gl_lds16(bg0 + k2, &Bs[i2 * 8192 + ub0 * 8]);
            gl_lds16(bg1 + k2, &Bs[i2 * 8192 + ub1 * 8]);
        }
        bf16x8 af[4], bw[4];
        #pragma unroll
        for (int i = 0; i < 4; i++) {
            af[i] = *(const bf16x8*)&As[i0 * 4096 + offA[i]];
            bw[i] = *(const bf16x8*)&Bs[i0 * 8192 + offB[i]];
        }
        PRIO1;
        #pragma unroll
        for (int mi = 0; mi < 4; mi++)
            #pragma unroll
            for (int ni = 0; ni < 4; ni++)
                acc[mi][ni] = __builtin_amdgcn_mfma_f32_16x16x32_bf16(af[mi], bw[ni], acc[mi][ni], 0, 0, 0);
        PRIO0;
        if (kt < 7) {
            if (more) { WAITV3; } else { WAITV0; }
            BAR;
        }
        int tmp = i0; i0 = i1; i1 = i2; i2 = tmp;
    }

    float pbv[4], g1v[4], be1v[4];
    #pragma unroll
    for (int ni = 0; ni < 4; ni++) {
        int col = wn + ni * 16 + (lane & 15);
        pbv[ni] = pb[col]; g1v[ni] = gamma[col]; be1v[ni] = beta[col];
    }
    #pragma unroll
    for (int mi = 0; mi < 4; mi++)
        #pragma unroll
        for (int rr = 0; rr < 4; rr++) {
            float s = 0.f, ss = 0.f;
            #pragma unroll
            for (int ni = 0; ni < 4; ni++) {
                float v = acc[mi][ni][rr] + pbv[ni];
                acc[mi][ni][rr] = v; s += v; ss += v * v;
            }
            #pragma unroll
            for (int off = 1; off <= 8; off <<= 1) { s += __shfl_xor(s, off); ss += __shfl_xor(ss, off); }
            if ((lane & 15) == 0) {
                int r = wm + mi * 16 + (lane >> 4) * 4 + rr;
                red_s[r][w & 3] = s; red_ss[r][w & 3] = ss;
            }
        }
    __syncthreads();
    #pragma unroll
    for (int mi = 0; mi < 4; mi++)
        #pragma unroll
        for (int rr = 0; rr < 4; rr++) {
            const int r = wm + mi * 16 + (lane >> 4) * 4 + rr;
            const float s = red_s[r][0] + red_s[r][1] + red_s[r][2] + red_s[r][3];
            const float ss = red_ss[r][0] + red_ss[r][1] + red_ss[r][2] + red_ss[r][3];
            const float mu = s * (1.0f / 256.0f);
            const float rstd = rsqrtf(ss * (1.0f / 256.0f) - mu * mu + 1e-5f);
            const long sp = srow_s[r];
            #pragma unroll
            for (int ni = 0; ni < 4; ni++) {
                int col = wn + ni * 16 + (lane & 15);
                float o = x[sp * 256 + col] + (acc[mi][ni][rr] - mu) * rstd * g1v[ni] + be1v[ni];
                x1b[sp * 256 + col] = f2bf(o);
            }
        }
}

// ------- mlp2ln2: 128x256 3-deep GEMM (K=1024) + LN2 + bf16 residual, fp32 out ----
__global__ __launch_bounds__(512)
void mlp2ln2(const ushort_t* __restrict__ A, const ushort_t* __restrict__ W,
             const float* __restrict__ pb, const ushort_t* __restrict__ x1res,
             const float* __restrict__ gamma, const float* __restrict__ beta,
             float* __restrict__ out)
{
    __shared__ ushort_t As[3 * 4096];
    __shared__ ushort_t Bs[3 * 8192];
    __shared__ float red_s[128][4];
    __shared__ float red_ss[128][4];
    const int t = threadIdx.x, lane = t & 63, w = t >> 6;
    const int row0 = blockIdx.x * 128;
    const int wm = (w >> 2) * 64, wn = (w & 3) * 64;

    const int ra0 = t >> 2, sa0 = ((t & 3) ^ ((ra0 >> 1) & 3)) * 8;
    const ushort_t* ag = A + (long)(row0 + ra0) * 1024 + sa0;
    const int ub0 = t, ub1 = t + 512;
    const int rb0 = ub0 >> 2, sb0 = ((ub0 & 3) ^ ((rb0 >> 1) & 3)) * 8;
    const int rb1 = ub1 >> 2, sb1 = ((ub1 & 3) ^ ((rb1 >> 1) & 3)) * 8;
    const ushort_t* bg0 = W + (long)rb0 * 1024 + sb0;
    const ushort_t* bg1 = W + (long)rb1 * 1024 + sb1;

    int offA[4], offB[4];
    #pragma unroll
    for (int i = 0; i < 4; i++) {
        int ra = wm + i * 16 + (lane & 15);
        offA[i] = ra * 32 + (((lane >> 4) ^ ((ra >> 1) & 3)) * 8);
        int rb = wn + i * 16 + (lane & 15);
        offB[i] = rb * 32 + (((lane >> 4) ^ ((rb >> 1) & 3)) * 8);
    }

    f32x4 acc[4][4] = {};
    gl_lds16(ag,       &As[t * 8]);
    gl_lds16(bg0,       &Bs[ub0 * 8]);
    gl_lds16(bg1,       &Bs[ub1 * 8]);
    gl_lds16(ag + 32,  &As[4096 + t * 8]);
    gl_lds16(bg0 + 32,  &Bs[8192 + ub0 * 8]);
    gl_lds16(bg1 + 32,  &Bs[8192 + ub1 * 8]);
    WAITV3; BAR;

    int i0 = 0, i1 = 1, i2 = 2;
    for (int kt = 0; kt < 32; kt++) {
        const bool more = (kt + 2 < 32);
        if (more) {
            const int k2 = (kt + 2) * 32;
            gl_lds16(ag + k2, &As[i2 * 4096 + t * 8]);
            gl_lds16(bg0 + k2, &Bs[i2 * 8192 + ub0 * 8]);
            gl_lds16(bg1 + k2, &Bs[i2 * 8192 + ub1 * 8]);
        }
        bf16x8 af[4], bw[4];
        #pragma unroll
        for (int i = 0; i < 4; i++) {
            af[i] = *(const bf16x8*)&As[i0 * 4096 + offA[i]];
            bw[i] = *(const bf16x8*)&Bs[i0 * 8192 + offB[i]];
        }
        PRIO1;
        #pragma unroll
        for (int mi = 0; mi < 4; mi++)
            #pragma unroll
            for (int ni = 0; ni < 4; ni++)
                acc[mi][ni] = __builtin_amdgcn_mfma_f32_16x16x32_bf16(af[mi], bw[ni], acc[mi][ni], 0, 0, 0);
        PRIO0;
        if (kt < 31) {
            if (more) { WAITV3; } else { WAITV0; }
            BAR;
        }
        int tmp = i0; i0 = i1; i1 = i2; i2 = tmp;
    }

    float pbv[4], g2v[4], be2v[4];
    #pragma unroll
    for (int ni = 0; ni < 4; ni++) {
        int col = wn + ni * 16 + (lane & 15);
        pbv[ni] = pb[col]; g2v[ni] = gamma[col]; be2v[ni] = beta[col];
    }
    #pragma unroll
    for (int mi = 0; mi < 4; mi++)
        #pragma unroll
        for (int rr = 0; rr < 4; rr++) {
            float s = 0.f, ss = 0.f;
            #pragma unroll
            for (int ni = 0; ni < 4; ni++) {
                float v = acc[mi][ni][rr] + pbv[ni];
                acc[mi][ni][rr] = v; s += v; ss += v * v;
            }
            #pragma unroll
            for (int off = 1; off <= 8; off <<= 1) { s += __shfl_xor(s, off); ss += __shfl_xor(ss, off); }
            if ((lane & 15) == 0) {
                int r = wm + mi * 16 + (lane >> 4) * 4 + rr;
                red_s[r][w & 3] = s; red_ss[r][w & 3] = ss;
            }
        }
    __syncthreads();
    #pragma unroll
    for (int mi = 0; mi < 4; mi++)
        #pragma unroll
        for (int rr = 0; rr < 4; rr++) {
            const int r = wm + mi * 16 + (lane >> 4) * 4 + rr;
            const float s = red_s[r][0] + red_s[r][1] + red_s[r][2] + red_s[r][3];
            const float ss = red_ss[r][0] + red_ss[r][1] + red_ss[r][2] + red_ss[r][3];
            const float mu = s * (1.0f / 256.0f);
            const float rstd = rsqrtf(ss * (1.0f / 256.0f) - mu * mu + 1e-5f);
            const long gr = row0 + r;
            #pragma unroll
            for (int ni = 0; ni < 4; ni++) {
                int col = wn + ni * 16 + (lane & 15);
                out[gr * 256 + col] = bf2f(x1res[gr * 256 + col])
                                    + (acc[mi][ni][rr] - mu) * rstd * g2v[ni] + be2v[ni];
            }
        }
}

extern "C" void kernel_launch(void* const* d_in, const int* in_sizes, int n_in,
                              void* d_out, int out_size, void* d_ws, size_t ws_size,
                              hipStream_t stream) {
    const float* x      = (const float*)d_in[0];
    const float* qkv_w  = (const float*)d_in[1];
    const float* qkv_b  = (const float*)d_in[2];
    const float* proj_w = (const float*)d_in[3];
    const float* proj_b = (const float*)d_in[4];
    const float* rpb    = (const float*)d_in[5];
    const float* gamma1 = (const float*)d_in[6];
    const float* beta1  = (const float*)d_in[7];
    const float* w1     = (const float*)d_in[8];
    const float* b1     = (const float*)d_in[9];
    const float* w2     = (const float*)d_in[10];
    const float* b2     = (const float*)d_in[11];
    const float* gamma2 = (const float*)d_in[12];
    const float* beta2  = (const float*)d_in[13];
    float* outf = (float*)d_out;

    // d_out[0,51.4M) holds attnout (bf16) until projln1 consumes it.
    ushort_t* attnout = (ushort_t*)d_out;

    char* ws = (char*)d_ws;
    ushort_t* qkvb  = (ushort_t*)ws;                      // [0,154.1M)   qkv -> attn (dead after)
    ushort_t* x1b   = (ushort_t*)ws;                      // [0,51.4M)    projln1 -> MLP (qkvb dead)
    ushort_t* hbuf  = (ushort_t*)(ws + 51380224ULL);      // [51.4,256.9M) full-M hidden
    ushort_t* wqkvb = (ushort_t*)(ws + 256901120ULL);     // bf16 weights [N][K]
    ushort_t* wprojb= (ushort_t*)(ws + 257294336ULL);
    ushort_t* w1t   = (ushort_t*)(ws + 257425408ULL);
    ushort_t* w2t   = (ushort_t*)(ws + 257949696ULL);

    const int M = 100352;
    dim3 blk(256);
    // prep: all bf16 weights in one dispatch
    convAll<<<dim3(3072), blk, 0, stream>>>(qkv_w, proj_w, w1, w2,
                                            wqkvb, wprojb, w1t, w2t);
    // 1. qkv = gather(x) @ Wqkv^T + b  (128x256 tile, fused gather, NCOLS=3)
    gemmW<0, 1, 3><<<dim3(2352), dim3(512), 0, stream>>>(x, wqkvb, qkv_b, qkvb, M, 768, 256);
    // 2. windowed attention
    attn_mfma<<<dim3(16384), dim3(64), 0, stream>>>(qkvb, rpb, attnout);
    // 3. proj + LN1 + residual -> x1 bf16 (scattered to natural row order)
    projln1<<<dim3(784), dim3(512), 0, stream>>>(attnout, wprojb, proj_b, x,
                                                 gamma1, beta1, x1b);
    // 4. h = gelu(x1 @ W1^T + b1), full M in one dispatch
    gemmW<1, 0, 4><<<dim3(3136), dim3(512), 0, stream>>>(x1b, w1t, b1, hbuf, M, 1024, 256);
    // 5. out = x1 + LN2(h @ W2^T + b2), full M in one dispatch
    mlp2ln2<<<dim3(784), dim3(512), 0, stream>>>(hbuf, w2t, b2, x1b,
                                                 gamma2, beta2, outf);
}